// Round 20
// baseline (192.024 us; speedup 1.0000x reference)
//
#include <hip/hip_runtime.h>
#include <hip/hip_bf16.h>

#define VOCAB 50000
#define EMBD  512
#define HID   1024
#define NB    256
#define SEQW  26
#define MTOT  (SEQW * NB)   /* 6656 */
#define NGATE (4 * HID)     /* 4096 */

#define TRB 6256            /* 782*8 transpose blocks */
#define CVB 4096            /* convw blocks */
#define INB 1024            /* init blocks */

typedef short short8 __attribute__((ext_vector_type(8)));
typedef _Float16 half8 __attribute__((ext_vector_type(8)));
typedef _Float16 half4 __attribute__((ext_vector_type(4)));
typedef float f32x4  __attribute__((ext_vector_type(4)));
typedef float f32x2  __attribute__((ext_vector_type(2)));

__device__ __forceinline__ unsigned short f16bits(_Float16 h) {
    union { _Float16 h; unsigned short u; } cv; cv.h = h; return cv.u;
}

__device__ __forceinline__ void gload16(const void* g, void* l) {
    __builtin_amdgcn_global_load_lds(
        (const __attribute__((address_space(1))) void*)g,
        (__attribute__((address_space(3))) void*)l, 16, 0, 0);
}

__device__ __forceinline__ float fsig(float x) {
    return __builtin_amdgcn_rcpf(1.0f + __expf(-x));
}
__device__ __forceinline__ float ftanh(float x) {
    return 2.0f * __builtin_amdgcn_rcpf(1.0f + __expf(-2.0f * x)) - 1.0f;
}

// ---------------- fused pre-kernel: transpose | convw | init ----------------
__global__ void pre_kernel(const float* __restrict__ W,
                           unsigned short* __restrict__ WT,
                           const float* __restrict__ Wih,
                           const float* __restrict__ Whh,
                           const float* __restrict__ b_ih,
                           const float* __restrict__ b_hh,
                           unsigned short* __restrict__ ih,
                           unsigned short* __restrict__ hh,
                           float* __restrict__ bsum,
                           unsigned short* __restrict__ hBuf,
                           unsigned int* __restrict__ bar) {
    int bx = blockIdx.x;
    int tid = threadIdx.x;
    if (bx < TRB) {
        __shared__ _Float16 tile[64][72];
        int v0 = (bx % 782) * 64;
        int e0 = (bx / 782) * 64;
        int e_loc = tid >> 2, q = tid & 3;
        int vq = q * 16;
        if (v0 + vq < VOCAB) {
            const float* src = W + (size_t)(e0 + e_loc) * VOCAB + v0 + vq;
            #pragma unroll
            for (int j = 0; j < 4; ++j) {
                f32x4 x = *(const f32x4*)(src + 4 * j);
                #pragma unroll
                for (int i = 0; i < 4; ++i)
                    tile[vq + 4 * j + i][e_loc] = (_Float16)x[i];
            }
        }
        __syncthreads();
        int v_loc = tid >> 2;
        int ec = q * 16;
        int v = v0 + v_loc;
        if (v < VOCAB) {
            short8* dst = (short8*)(WT + (size_t)v * EMBD + e0 + ec);
            dst[0] = *(const short8*)&tile[v_loc][ec];
            dst[1] = *(const short8*)&tile[v_loc][ec + 8];
        }
    } else if (bx < TRB + CVB) {
        int j = bx - TRB;  // 0..4095
        if (tid == 0) bsum[j] = b_ih[j] + b_hh[j];
        for (int col = tid; col < EMBD; col += blockDim.x)
            ih[(size_t)j * EMBD + col] = f16bits((_Float16)Wih[(size_t)j * EMBD + col]);
        for (int col = tid; col < HID; col += blockDim.x)
            hh[(size_t)j * HID + col] = f16bits((_Float16)Whh[(size_t)j * HID + col]);
    } else {
        int idx = (bx - TRB - CVB) * 256 + tid;   // over NB*HID
        hBuf[idx] = 0;
        if (idx < 4096) bar[idx] = 0;
    }
}

// ---------------- embedding: row-gather from WT + tanh -> fp16 --------------
__global__ void embed_kernel(const int* __restrict__ qv,
                             const unsigned short* __restrict__ WT,
                             unsigned short* __restrict__ eHi) {
    int pair = blockIdx.x * 4 + (threadIdx.x >> 6);
    int t = pair >> 8, b = pair & 255;
    int lane = threadIdx.x & 63;
    int tok = qv[b * SEQW + t];
    short8 out = {};
    if (tok > 0) {
        short8 v = *(const short8*)(WT + (size_t)(tok - 1) * EMBD + lane * 8);
        #pragma unroll
        for (int i = 0; i < 8; ++i) {
            union { short s; _Float16 h; } cv; cv.s = v[i];
            out[i] = (short)f16bits((_Float16)tanhf((float)cv.h));
        }
    }
    *(short8*)(eHi + (size_t)pair * EMBD + lane * 8) = out;
}

// ---------------- pre-GEMM: LDS-staged, G0 fp16, INTERLEAVED [jl][gate] -----
__global__ __launch_bounds__(512, 2) void pregemm_kernel(
    const unsigned short* __restrict__ eHi,
    const unsigned short* __restrict__ ih,
    const float* __restrict__ bsum,
    unsigned short* __restrict__ G0h)
{
    __shared__ char smem[65536];   // A dbuf [2][16KB] @0, B dbuf [2][16KB] @32768

    int id = blockIdx.x;
    int xcd = id & 7, lid = id >> 3;
    int pc = xcd * 4 + (lid & 3);   // 0..31
    int pm = lid >> 2;              // 0..51
    int m0 = pm * 128;

    int tid = threadIdx.x;
    int w = tid >> 6;               // 0..7
    int mh = w >> 2, nh = w & 3;
    int lane = tid & 63;
    int col16 = lane & 15, g4 = lane >> 4;

    int sr = lane >> 3, sc = lane & 7;
    int ra0 = w * 16 + sr, ra1 = ra0 + 8;
    const char* eB = (const char*)eHi;
    const char* iB = (const char*)ih;
    size_t aOffG0 = (size_t)(m0 + ra0) * 1024 + (size_t)(((sc ^ (ra0 & 7))) * 16);
    size_t aOffG1 = (size_t)(m0 + ra1) * 1024 + (size_t)(((sc ^ (ra1 & 7))) * 16);
    int gb0 = (ra0 >> 5) * 1024 + pc * 32 + (ra0 & 31);
    int gb1 = (ra1 >> 5) * 1024 + pc * 32 + (ra1 & 31);
    size_t bOffG0 = (size_t)gb0 * 1024 + (size_t)(((sc ^ (ra0 & 7))) * 16);
    size_t bOffG1 = (size_t)gb1 * 1024 + (size_t)(((sc ^ (ra1 & 7))) * 16);
    int ldsRow0 = (w * 16) * 128;
    int ldsRow1 = (w * 16 + 8) * 128;

    f32x4 acc[4][2];
    #pragma unroll
    for (int fm = 0; fm < 4; ++fm)
        #pragma unroll
        for (int fn = 0; fn < 2; ++fn)
            acc[fm][fn] = (f32x4){0.f, 0.f, 0.f, 0.f};

    int swb = col16 & 7;
    int aRow[4], bRow[2];
    #pragma unroll
    for (int fm = 0; fm < 4; ++fm) aRow[fm] = (mh * 64 + fm * 16 + col16) * 128;
    #pragma unroll
    for (int fn = 0; fn < 2; ++fn) bRow[fn] = (nh * 32 + fn * 16 + col16) * 128;

#define STAGE(kb, buf) do { \
        int kby = (kb) * 128; \
        char* aD = smem + (buf) * 16384; \
        char* bD = smem + 32768 + (buf) * 16384; \
        gload16(eB + aOffG0 + kby, aD + ldsRow0); \
        gload16(eB + aOffG1 + kby, aD + ldsRow1); \
        gload16(iB + bOffG0 + kby, bD + ldsRow0); \
        gload16(iB + bOffG1 + kby, bD + ldsRow1); \
    } while (0)

    STAGE(0, 0);
    #pragma unroll
    for (int kb = 0; kb < 8; ++kb) {
        int cur = kb & 1;
        __syncthreads();
        if (kb < 7) STAGE(kb + 1, cur ^ 1);
        const char* aS = smem + cur * 16384;
        const char* bS = smem + 32768 + cur * 16384;
        #pragma unroll
        for (int kk = 0; kk < 2; ++kk) {
            int co = ((kk * 4 + g4) ^ swb) * 16;
            half8 bF[2];
            #pragma unroll
            for (int fn = 0; fn < 2; ++fn)
                bF[fn] = *(const half8*)(const void*)(bS + bRow[fn] + co);
            #pragma unroll
            for (int fm = 0; fm < 4; ++fm) {
                half8 aF = *(const half8*)(const void*)(aS + aRow[fm] + co);
                #pragma unroll
                for (int fn = 0; fn < 2; ++fn)
                    acc[fm][fn] = __builtin_amdgcn_mfma_f32_16x16x32_f16(
                        aF, bF[fn], acc[fm][fn], 0, 0, 0);
            }
        }
    }
#undef STAGE

    // epilogue: G0h[t][ct][b][jl*4 + gate] fp16 (+bias)
    #pragma unroll
    for (int fn = 0; fn < 2; ++fn) {
        int cp = nh * 32 + fn * 16 + col16;
        int gate = cp >> 5;
        int jh = pc * 32 + (cp & 31);
        int ct = jh >> 4, jl = jh & 15;
        int cidx = jl * 4 + gate;
        float bv = bsum[gate * HID + jh];
        #pragma unroll
        for (int fm = 0; fm < 4; ++fm)
            #pragma unroll
            for (int r = 0; r < 4; ++r) {
                int row = m0 + mh * 64 + fm * 16 + g4 * 4 + r;
                int t = row >> 8, b = row & 255;
                G0h[(((size_t)t * 64 + ct) * 256 + b) * 64 + cidx] =
                    f16bits((_Float16)(acc[fm][fn][r] + bv));
            }
    }
}

// ---------------- persistent LSTM: paired 16-row groups, hidden barrier -----
// 256 blocks x 512 threads. Block bx: k = bx&7 (XCD), lid = bx>>3 (128 cols).
// Two groups per block: gA = 2k (rows k*32..+16), gB = 2k+1 (rows +16..+32).
// Phases alternate A(t), B(t): a group's flag-poll at step t runs one full
// phase after its peers set the flags -> poll returns immediately; barrier
// latency hides under the other group's compute. A group's flag(t+1) store
// is deferred to the next phase's first syncthreads (which drains the sc1
// h-stores -> flag implies h L3-visible). 8 waves = kq(4) x ch(2); M=16
// (one M-frag); B-regs shared across phases (same cols).
__global__ __launch_bounds__(512, 2) void lstm_persist(
    const unsigned short* __restrict__ hh,     // fp16 Whh [4096][1024]
    unsigned short* __restrict__ hBuf,         // 27 slots of NB*HID fp16
    const unsigned short* __restrict__ G0h,    // fp16 G0 [t][ct][b][jl*4+gate]
    float* __restrict__ out,
    unsigned int* __restrict__ bar)
{
    extern __shared__ char smem[];
    // [0,32768): A-stage [16][2048B] XOR-swizzled
    // [32768,66560): gbuf[4][16][132] f32
    float* gbuf = (float*)(smem + 32768);

    int bx = blockIdx.x;
    int k   = bx & 7;                 // XCD-local
    int lid = bx >> 3;                // 0..31
    int jh0 = lid * 32;

    int tid = threadIdx.x;
    int w = tid >> 6;
    int kq = w & 3, ch = w >> 2;      // K-quarter, col-half
    int lane = tid & 63;
    int col16 = lane & 15, g4 = lane >> 4;

    int m0p[2]  = { k * 32, k * 32 + 16 };
    unsigned int* flg[2] = { bar + (2 * k) * 32, bar + (2 * k + 1) * 32 };

    // ---- preload B: wave's 64 gate-cols x K-quarter (256) into regs ----
    half8 bB[4][8];
    #pragma unroll
    for (int nf = 0; nf < 4; ++nf) {
        int colp = ch * 64 + nf * 16 + col16;      // 0..127
        int gate = colp >> 5, c32 = colp & 31;
        const char* bRow = (const char*)hh +
            ((size_t)(gate * HID + jh0 + c32) * HID + kq * 256 + g4 * 8) * 2;
        #pragma unroll
        for (int kk = 0; kk < 8; ++kk)
            bB[nf][kk] = *(const half8*)(const void*)(bRow + kk * 64);
    }

    int swr = (col16 & 7) << 4;
    int ml = tid >> 5, jl = tid & 31;          // epilogue cell: 16 rows x 32 jh
    int jh = jh0 + jl;
    int ctE = jh >> 4, jlE = jh & 15;

    float cR[2] = {0.f, 0.f};
    unsigned int* pendPtr = 0;
    unsigned int pendVal = 0;

    for (int t = 0; t < SEQW; ++t) {
        const unsigned short* hIn = hBuf + (size_t)t * NB * HID;
        unsigned short* hOut = hBuf + (size_t)(t + 1) * NB * HID;

        #pragma unroll
        for (int ph = 0; ph < 2; ++ph) {
            int m0 = m0p[ph];

            // G0 prefetch (constant data; hides under poll/stage/K-loop)
            half4 g0;
            {
                const unsigned short* pg = G0h +
                    (((size_t)t * 64 + ctE) * 256 + (m0 + ml)) * 64 + jlE * 4;
                g0 = *(const half4*)(const void*)pg;
            }

            // poll this group's readiness (peers set flags one phase ago)
            if (t > 0 && w == 0) {
                unsigned int tv = (unsigned int)t;
                for (;;) {
                    unsigned int v = __hip_atomic_load(
                        flg[ph] + (lane & 31), __ATOMIC_RELAXED,
                        __HIP_MEMORY_SCOPE_AGENT);
                    if (__all(v >= tv)) break;
                    __builtin_amdgcn_s_sleep(1);
                }
            }
            __syncthreads();   // (a) poll done; prev epilogue/h-stores drained

            // deferred flag store for the PREVIOUS phase's group
            if (pendPtr && tid == 0)
                __hip_atomic_store(pendPtr, pendVal,
                                   __ATOMIC_RELAXED, __HIP_MEMORY_SCOPE_AGENT);
            pendPtr = 0;

            f32x4 acc[4];
            #pragma unroll
            for (int nf = 0; nf < 4; ++nf)
                acc[nf] = (f32x4){0.f, 0.f, 0.f, 0.f};

            if (t > 0) {
                // stage 16 rows (32KB) via global_load_lds; wave w: rows 2w,2w+1
                #pragma unroll
                for (int j = 0; j < 4; ++j) {
                    int row = w * 2 + (j >> 1);
                    int half_ = j & 1;
                    int cs = (half_ * 64 + lane) ^ (row & 7);
                    gload16((const char*)hIn + (size_t)(m0 + row) * 2048 + cs * 16,
                            smem + row * 2048 + half_ * 1024);
                }
                __syncthreads();   // (b) stage drained

                // K loop: A from LDS (M=16), B from registers
                #pragma unroll
                for (int kk = 0; kk < 8; ++kk) {
                    int kb = kq * 512 + kk * 64 + g4 * 16;
                    half8 a0 = *(const half8*)(const void*)(
                        smem + col16 * 2048 + (kb ^ swr));
                    #pragma unroll
                    for (int nf = 0; nf < 4; ++nf)
                        acc[nf] = __builtin_amdgcn_mfma_f32_16x16x32_f16(
                            a0, bB[nf][kk], acc[nf], 0, 0, 0);
                }
            }
            __syncthreads();   // (c) A reads done; all waves ready

            // scatter K-partials: gbuf[kq][row16][132]
            #pragma unroll
            for (int nf = 0; nf < 4; ++nf) {
                int colp = ch * 64 + nf * 16 + col16;
                #pragma unroll
                for (int r = 0; r < 4; ++r)
                    gbuf[(kq * 16 + g4 * 4 + r) * 132 + colp] = acc[nf][r];
            }
            __syncthreads();   // (d) gbuf complete

            // epilogue: 1 cell/thread
            float gv[4];
            #pragma unroll
            for (int g = 0; g < 4; ++g) {
                float s = 0.f;
                #pragma unroll
                for (int q = 0; q < 4; ++q)
                    s += gbuf[(q * 16 + ml) * 132 + g * 32 + jl];
                gv[g] = s + (float)g0[g];
            }
            float si = fsig(gv[0]);
            float sf = fsig(gv[1]);
            float tg = ftanh(gv[2]);
            float so = fsig(gv[3]);
            float cN = sf * cR[ph] + si * tg;
            float hN = so * ftanh(cN);
            cR[ph] = cN;

            size_t p = (size_t)(m0 + ml) * HID + jh;
            if (t == SEQW - 1) {
                out[p] = hN;
            } else {
                __hip_atomic_store((unsigned short*)(hOut + p),
                                   f16bits((_Float16)hN),
                                   __ATOMIC_RELAXED, __HIP_MEMORY_SCOPE_AGENT);
                pendPtr = flg[ph] + lid;
                pendVal = (unsigned int)(t + 1);
            }
        }
    }
}

extern "C" void kernel_launch(void* const* d_in, const int* in_sizes, int n_in,
                              void* d_out, int out_size, void* d_ws, size_t ws_size,
                              hipStream_t stream) {
    const int*   qv   = (const int*)d_in[0];
    const float* Wemb = (const float*)d_in[2];
    const float* Wih  = (const float*)d_in[3];
    const float* Whh  = (const float*)d_in[4];
    const float* b_ih = (const float*)d_in[5];
    const float* b_hh = (const float*)d_in[6];
    float* out = (float*)d_out;

    char* ws = (char*)d_ws;
    size_t off = 0;
    unsigned short* eHi  = (unsigned short*)(ws + off); off += (size_t)MTOT * EMBD * 2;
    unsigned short* ih   = (unsigned short*)(ws + off); off += (size_t)NGATE * EMBD * 2;
    unsigned short* hh   = (unsigned short*)(ws + off); off += (size_t)NGATE * HID * 2;
    unsigned short* hBuf = (unsigned short*)(ws + off); off += (size_t)(SEQW + 1) * NB * HID * 2;
    float* bsum          = (float*)(ws + off);          off += (size_t)NGATE * 4;
    unsigned int* bar    = (unsigned int*)(ws + off);   off += 16384;
    off = (off + 255) & ~(size_t)255;
    unsigned short* G0h  = (unsigned short*)(ws + off); off += (size_t)MTOT * NGATE * 2; // 54.5 MB
    unsigned short* WembT = (unsigned short*)G0h;       // aliases G0h (dead before pregemm)

    pre_kernel<<<TRB + CVB + INB, 256, 0, stream>>>(
        Wemb, WembT, Wih, Whh, b_ih, b_hh, ih, hh, bsum, hBuf, bar);
    embed_kernel<<<MTOT / 4, 256, 0, stream>>>(qv, WembT, eHi);
    pregemm_kernel<<<1664, 512, 0, stream>>>(eHi, ih, bsum, G0h);

    lstm_persist<<<256, 512, 66560, stream>>>(hh, hBuf, G0h, out, bar);
}

// Round 22
// 186.940 us; speedup vs baseline: 1.0272x; 1.0272x over previous
//
#include <hip/hip_runtime.h>
#include <hip/hip_bf16.h>

#define VOCAB 50000
#define EMBD  512
#define HID   1024
#define NB    256
#define SEQW  26
#define MTOT  (SEQW * NB)   /* 6656 */
#define NGATE (4 * HID)     /* 4096 */

#define TRB 6256            /* 782*8 transpose blocks */
#define CVB 4096            /* convw blocks */
#define INB 1024            /* init blocks */

typedef short short8 __attribute__((ext_vector_type(8)));
typedef _Float16 half8 __attribute__((ext_vector_type(8)));
typedef float f32x4  __attribute__((ext_vector_type(4)));
typedef float f32x2  __attribute__((ext_vector_type(2)));

__device__ __forceinline__ unsigned short f16bits(_Float16 h) {
    union { _Float16 h; unsigned short u; } cv; cv.h = h; return cv.u;
}

__device__ __forceinline__ void gload16(const void* g, void* l) {
    __builtin_amdgcn_global_load_lds(
        (const __attribute__((address_space(1))) void*)g,
        (__attribute__((address_space(3))) void*)l, 16, 0, 0);
}

__device__ __forceinline__ float fsig(float x) {
    return __builtin_amdgcn_rcpf(1.0f + __expf(-x));
}
__device__ __forceinline__ float ftanh(float x) {
    return 2.0f * __builtin_amdgcn_rcpf(1.0f + __expf(-2.0f * x)) - 1.0f;
}

// ------- fused pre-kernel: transpose(+tanh) | convw | init(+zrow) -----------
__global__ void pre_kernel(const float* __restrict__ W,
                           unsigned short* __restrict__ WT,
                           const float* __restrict__ Wih,
                           const float* __restrict__ Whh,
                           const float* __restrict__ b_ih,
                           const float* __restrict__ b_hh,
                           unsigned short* __restrict__ ih,
                           unsigned short* __restrict__ hh,
                           float* __restrict__ bsum,
                           unsigned short* __restrict__ hBuf,
                           unsigned int* __restrict__ bar,
                           unsigned short* __restrict__ zrow) {
    int bx = blockIdx.x;
    int tid = threadIdx.x;
    if (bx < TRB) {
        // WT[v][e] = fp16(tanh(Wemb[e][v])) — tanh hidden under BW
        __shared__ _Float16 tile[64][72];
        int v0 = (bx % 782) * 64;
        int e0 = (bx / 782) * 64;
        int e_loc = tid >> 2, q = tid & 3;
        int vq = q * 16;
        if (v0 + vq < VOCAB) {
            const float* src = W + (size_t)(e0 + e_loc) * VOCAB + v0 + vq;
            #pragma unroll
            for (int j = 0; j < 4; ++j) {
                f32x4 x = *(const f32x4*)(src + 4 * j);
                #pragma unroll
                for (int i = 0; i < 4; ++i)
                    tile[vq + 4 * j + i][e_loc] = (_Float16)ftanh(x[i]);
            }
        }
        __syncthreads();
        int v_loc = tid >> 2;
        int ec = q * 16;
        int v = v0 + v_loc;
        if (v < VOCAB) {
            short8* dst = (short8*)(WT + (size_t)v * EMBD + e0 + ec);
            dst[0] = *(const short8*)&tile[v_loc][ec];
            dst[1] = *(const short8*)&tile[v_loc][ec + 8];
        }
    } else if (bx < TRB + CVB) {
        int j = bx - TRB;  // 0..4095
        if (tid == 0) bsum[j] = b_ih[j] + b_hh[j];
        for (int col = tid; col < EMBD; col += blockDim.x)
            ih[(size_t)j * EMBD + col] = f16bits((_Float16)Wih[(size_t)j * EMBD + col]);
        for (int col = tid; col < HID; col += blockDim.x)
            hh[(size_t)j * HID + col] = f16bits((_Float16)Whh[(size_t)j * HID + col]);
    } else {
        int idx = (bx - TRB - CVB) * 256 + tid;   // over NB*HID
        hBuf[idx] = 0;
        if (idx < 4096) bar[idx] = 0;
        if (idx < 512) zrow[idx] = 0;
    }
}

// ------- pre-GEMM: token-indirect A-stage, LDS-staged, G0 fp16 [jl][gate] ---
__global__ __launch_bounds__(512, 2) void pregemm_kernel(
    const int* __restrict__ qv,
    const unsigned short* __restrict__ WT,    // tanh'd embeddings [50000][512]
    const unsigned short* __restrict__ zrow,  // 1KB zeros (pad token)
    const unsigned short* __restrict__ ih,
    const float* __restrict__ bsum,
    unsigned short* __restrict__ G0h)
{
    __shared__ char smem[65536];   // A dbuf [2][16KB] @0, B dbuf [2][16KB] @32768

    int id = blockIdx.x;
    int xcd = id & 7, lid = id >> 3;
    int pc = xcd * 4 + (lid & 3);   // 0..31
    int pm = lid >> 2;              // 0..51
    int m0 = pm * 128;

    int tid = threadIdx.x;
    int w = tid >> 6;               // 0..7
    int mh = w >> 2, nh = w & 3;
    int lane = tid & 63;
    int col16 = lane & 15, g4 = lane >> 4;

    int sr = lane >> 3, sc = lane & 7;
    int ra0 = w * 16 + sr, ra1 = ra0 + 8;

    // token-indirect A sources (swizzled chunk within row, per G21)
    int row0 = m0 + ra0, row1 = m0 + ra1;
    int tok0 = qv[(row0 & 255) * SEQW + (row0 >> 8)];
    int tok1 = qv[(row1 & 255) * SEQW + (row1 >> 8)];
    const char* srcA0 = (tok0 > 0)
        ? (const char*)WT + (size_t)(tok0 - 1) * 1024 + ((sc ^ (ra0 & 7)) * 16)
        : (const char*)zrow + ((sc ^ (ra0 & 7)) * 16);
    const char* srcA1 = (tok1 > 0)
        ? (const char*)WT + (size_t)(tok1 - 1) * 1024 + ((sc ^ (ra1 & 7)) * 16)
        : (const char*)zrow + ((sc ^ (ra1 & 7)) * 16);

    const char* iB = (const char*)ih;
    int gb0 = (ra0 >> 5) * 1024 + pc * 32 + (ra0 & 31);
    int gb1 = (ra1 >> 5) * 1024 + pc * 32 + (ra1 & 31);
    size_t bOffG0 = (size_t)gb0 * 1024 + (size_t)(((sc ^ (ra0 & 7))) * 16);
    size_t bOffG1 = (size_t)gb1 * 1024 + (size_t)(((sc ^ (ra1 & 7))) * 16);
    int ldsRow0 = (w * 16) * 128;
    int ldsRow1 = (w * 16 + 8) * 128;

    f32x4 acc[4][2];
    #pragma unroll
    for (int fm = 0; fm < 4; ++fm)
        #pragma unroll
        for (int fn = 0; fn < 2; ++fn)
            acc[fm][fn] = (f32x4){0.f, 0.f, 0.f, 0.f};

    int swb = col16 & 7;
    int aRow[4], bRow[2];
    #pragma unroll
    for (int fm = 0; fm < 4; ++fm) aRow[fm] = (mh * 64 + fm * 16 + col16) * 128;
    #pragma unroll
    for (int fn = 0; fn < 2; ++fn) bRow[fn] = (nh * 32 + fn * 16 + col16) * 128;

#define STAGE(kb, buf) do { \
        int kby = (kb) * 128; \
        char* aD = smem + (buf) * 16384; \
        char* bD = smem + 32768 + (buf) * 16384; \
        gload16(srcA0 + kby, aD + ldsRow0); \
        gload16(srcA1 + kby, aD + ldsRow1); \
        gload16(iB + bOffG0 + kby, bD + ldsRow0); \
        gload16(iB + bOffG1 + kby, bD + ldsRow1); \
    } while (0)

    STAGE(0, 0);
    #pragma unroll
    for (int kb = 0; kb < 8; ++kb) {
        int cur = kb & 1;
        __syncthreads();
        if (kb < 7) STAGE(kb + 1, cur ^ 1);
        const char* aS = smem + cur * 16384;
        const char* bS = smem + 32768 + cur * 16384;
        #pragma unroll
        for (int kk = 0; kk < 2; ++kk) {
            int co = ((kk * 4 + g4) ^ swb) * 16;
            half8 bF[2];
            #pragma unroll
            for (int fn = 0; fn < 2; ++fn)
                bF[fn] = *(const half8*)(const void*)(bS + bRow[fn] + co);
            #pragma unroll
            for (int fm = 0; fm < 4; ++fm) {
                half8 aF = *(const half8*)(const void*)(aS + aRow[fm] + co);
                #pragma unroll
                for (int fn = 0; fn < 2; ++fn)
                    acc[fm][fn] = __builtin_amdgcn_mfma_f32_16x16x32_f16(
                        aF, bF[fn], acc[fm][fn], 0, 0, 0);
            }
        }
    }
#undef STAGE

    // epilogue: G0h[t][ct][b][jl*4 + gate] fp16 (+bias)
    #pragma unroll
    for (int fn = 0; fn < 2; ++fn) {
        int cp = nh * 32 + fn * 16 + col16;
        int gate = cp >> 5;
        int jh = pc * 32 + (cp & 31);
        int ct = jh >> 4, jl = jh & 15;
        int cidx = jl * 4 + gate;
        float bv = bsum[gate * HID + jh];
        #pragma unroll
        for (int fm = 0; fm < 4; ++fm)
            #pragma unroll
            for (int r = 0; r < 4; ++r) {
                int row = m0 + mh * 64 + fm * 16 + g4 * 4 + r;
                int t = row >> 8, b = row & 255;
                G0h[(((size_t)t * 64 + ct) * 256 + b) * 64 + cidx] =
                    f16bits((_Float16)(acc[fm][fn][r] + bv));
            }
    }
}

// ------- persistent LSTM: R19 structure, separate gbuf (one sync fewer) -----
__global__ __launch_bounds__(512, 2) void lstm_persist(
    const unsigned short* __restrict__ hh,     // fp16 Whh [4096][1024]
    unsigned short* __restrict__ hBuf,         // 27 slots of NB*HID fp16
    const unsigned short* __restrict__ G0h,    // fp16 G0 [t][ct][b][jl*4+gate]
    float* __restrict__ out,
    unsigned int* __restrict__ bar)
{
    extern __shared__ char smem[];
    // [0,65536): A [32][2048B] XOR-swizzled; [65536,133120): gbuf[4][32][132]
    float* gbuf = (float*)(smem + 65536);

    int bx = blockIdx.x;
    int grp = bx & 7;                 // XCD-local group
    int lid = bx >> 3;                // 0..31
    int m0  = grp * 32;
    int jh0 = lid * 32;

    int tid = threadIdx.x;
    int w = tid >> 6;
    int kq = w & 3, ch = w >> 2;      // K-quarter, col-half
    int lane = tid & 63;
    int col16 = lane & 15, g4 = lane >> 4;

    unsigned int* flags = bar + grp * 32;   // 32 packed flags (2 lines)

    // ---- preload B: wave's 64 gate-cols x K-quarter (256) into regs ----
    half8 bB[4][8];
    #pragma unroll
    for (int nf = 0; nf < 4; ++nf) {
        int colp = ch * 64 + nf * 16 + col16;      // 0..127
        int gate = colp >> 5, c32 = colp & 31;
        const char* bRow = (const char*)hh +
            ((size_t)(gate * HID + jh0 + c32) * HID + kq * 256 + g4 * 8) * 2;
        #pragma unroll
        for (int kk = 0; kk < 8; ++kk)
            bB[nf][kk] = *(const half8*)(const void*)(bRow + kk * 64);
    }

    int swr = (col16 & 7) << 4;
    int ml = tid >> 4, sc16 = tid & 15, jl2 = sc16 * 2;
    int jh = jh0 + jl2;
    int ctE = jh >> 4, jlE = jh & 15;

    float cReg[2] = {0.f, 0.f};

    for (int t = 0; t < SEQW; ++t) {
        const unsigned short* hIn = hBuf + (size_t)t * NB * HID;
        unsigned short* hOut = hBuf + (size_t)(t + 1) * NB * HID;

        // ---- G0 prefetch: ONE 16B load ----
        half8 g0;
        {
            const unsigned short* pg = G0h +
                (((size_t)t * 64 + ctE) * 256 + (m0 + ml)) * 64 + jlE * 4;
            g0 = *(const half8*)(const void*)pg;
        }

        f32x4 acc[2][4];
        #pragma unroll
        for (int mf = 0; mf < 2; ++mf)
            #pragma unroll
            for (int nf = 0; nf < 4; ++nf)
                acc[mf][nf] = (f32x4){0.f, 0.f, 0.f, 0.f};

        if (t > 0) {
            // A stage via global_load_lds (linear dest, swizzled source)
            #pragma unroll
            for (int j = 0; j < 8; ++j) {
                int row = w * 4 + (j >> 1);
                int half_ = j & 1;
                int cs = (half_ * 64 + lane) ^ (row & 7);
                gload16((const char*)hIn + (size_t)(m0 + row) * 2048 + cs * 16,
                        smem + row * 2048 + half_ * 1024);
            }
            __syncthreads();   // drains global_load_lds before reads

            #pragma unroll
            for (int kk = 0; kk < 8; ++kk) {
                int kb = kq * 512 + kk * 64 + g4 * 16;
                int kbs = kb ^ swr;
                half8 a0 = *(const half8*)(const void*)(smem + col16 * 2048 + kbs);
                half8 a1 = *(const half8*)(const void*)(smem + (col16 + 16) * 2048 + kbs);
                #pragma unroll
                for (int nf = 0; nf < 4; ++nf) {
                    acc[0][nf] = __builtin_amdgcn_mfma_f32_16x16x32_f16(a0, bB[nf][kk], acc[0][nf], 0, 0, 0);
                    acc[1][nf] = __builtin_amdgcn_mfma_f32_16x16x32_f16(a1, bB[nf][kk], acc[1][nf], 0, 0, 0);
                }
            }
        }

        // scatter K-partials (gbuf separate region: no anti-alias sync)
        #pragma unroll
        for (int mf = 0; mf < 2; ++mf)
            #pragma unroll
            for (int nf = 0; nf < 4; ++nf) {
                int colp = ch * 64 + nf * 16 + col16;
                #pragma unroll
                for (int r = 0; r < 4; ++r)
                    gbuf[(kq * 32 + mf * 16 + g4 * 4 + r) * 132 + colp] = acc[mf][nf][r];
            }
        __syncthreads();

        float gv[4][2];
        #pragma unroll
        for (int g = 0; g < 4; ++g) {
            f32x2 s = {0.f, 0.f};
            #pragma unroll
            for (int q = 0; q < 4; ++q)
                s += *(const f32x2*)&gbuf[(q * 32 + ml) * 132 + g * 32 + jl2];
            gv[g][0] = s[0] + (float)g0[g];
            gv[g][1] = s[1] + (float)g0[4 + g];
        }

        float hN[2];
        #pragma unroll
        for (int u = 0; u < 2; ++u) {
            float si = fsig(gv[0][u]);
            float sf = fsig(gv[1][u]);
            float tg = ftanh(gv[2][u]);
            float so = fsig(gv[3][u]);
            float cN = sf * cReg[u] + si * tg;
            hN[u] = so * ftanh(cN);
            cReg[u] = cN;
        }
        size_t p = (size_t)(m0 + ml) * HID + jh;
        if (t == SEQW - 1) {
            *(f32x2*)(out + p) = (f32x2){hN[0], hN[1]};
        } else {
            unsigned int hv = (unsigned int)f16bits((_Float16)hN[0]) |
                              ((unsigned int)f16bits((_Float16)hN[1]) << 16);
            __hip_atomic_store((unsigned int*)(hOut + p), hv,
                               __ATOMIC_RELAXED, __HIP_MEMORY_SCOPE_AGENT);

            __syncthreads();   // ALL waves' h sc1-stores drained (L3-visible)
            unsigned int t1 = (unsigned int)(t + 1);
            if (tid == 0)
                __hip_atomic_store(flags + lid, t1,
                                   __ATOMIC_RELAXED, __HIP_MEMORY_SCOPE_AGENT);
            if (w == 0) {
                for (;;) {
                    unsigned int v = __hip_atomic_load(
                        flags + (lane & 31), __ATOMIC_RELAXED,
                        __HIP_MEMORY_SCOPE_AGENT);
                    if (__all(v >= t1)) break;
                    __builtin_amdgcn_s_sleep(1);
                }
            }
            __syncthreads();
        }
    }
}

extern "C" void kernel_launch(void* const* d_in, const int* in_sizes, int n_in,
                              void* d_out, int out_size, void* d_ws, size_t ws_size,
                              hipStream_t stream) {
    const int*   qv   = (const int*)d_in[0];
    const float* Wemb = (const float*)d_in[2];
    const float* Wih  = (const float*)d_in[3];
    const float* Whh  = (const float*)d_in[4];
    const float* b_ih = (const float*)d_in[5];
    const float* b_hh = (const float*)d_in[6];
    float* out = (float*)d_out;

    char* ws = (char*)d_ws;
    size_t off = 0;
    unsigned short* WT   = (unsigned short*)(ws + off); off += (size_t)VOCAB * EMBD * 2;  // 51.2 MB
    unsigned short* ih   = (unsigned short*)(ws + off); off += (size_t)NGATE * EMBD * 2;
    unsigned short* hh   = (unsigned short*)(ws + off); off += (size_t)NGATE * HID * 2;
    unsigned short* hBuf = (unsigned short*)(ws + off); off += (size_t)(SEQW + 1) * NB * HID * 2;
    float* bsum          = (float*)(ws + off);          off += (size_t)NGATE * 4;
    unsigned int* bar    = (unsigned int*)(ws + off);   off += 16384;
    unsigned short* zrow = (unsigned short*)(ws + off); off += 1024;
    off = (off + 255) & ~(size_t)255;
    unsigned short* G0h  = (unsigned short*)(ws + off); off += (size_t)MTOT * NGATE * 2;  // 54.5 MB

    pre_kernel<<<TRB + CVB + INB, 256, 0, stream>>>(
        Wemb, WT, Wih, Whh, b_ih, b_hh, ih, hh, bsum, hBuf, bar, zrow);
    pregemm_kernel<<<1664, 512, 0, stream>>>(qv, WT, zrow, ih, bsum, G0h);

    lstm_persist<<<256, 512, 133120, stream>>>(hh, hBuf, G0h, out, bar);
}

// Round 23
// 185.837 us; speedup vs baseline: 1.0333x; 1.0059x over previous
//
#include <hip/hip_runtime.h>
#include <hip/hip_bf16.h>

#define VOCAB 50000
#define EMBD  512
#define HID   1024
#define NB    256
#define SEQW  26
#define MTOT  (SEQW * NB)   /* 6656 */
#define NGATE (4 * HID)     /* 4096 */

#define TRB 6256            /* 782*8 transpose blocks */
#define CVB 4096            /* convw blocks */
#define INB 1024            /* init blocks */

typedef short short8 __attribute__((ext_vector_type(8)));
typedef _Float16 half8 __attribute__((ext_vector_type(8)));
typedef float f32x4  __attribute__((ext_vector_type(4)));
typedef float f32x2  __attribute__((ext_vector_type(2)));

__device__ __forceinline__ unsigned short f16bits(_Float16 h) {
    union { _Float16 h; unsigned short u; } cv; cv.h = h; return cv.u;
}

__device__ __forceinline__ void gload16(const void* g, void* l) {
    __builtin_amdgcn_global_load_lds(
        (const __attribute__((address_space(1))) void*)g,
        (__attribute__((address_space(3))) void*)l, 16, 0, 0);
}

__device__ __forceinline__ float fsig(float x) {
    return __builtin_amdgcn_rcpf(1.0f + __expf(-x));
}
__device__ __forceinline__ float ftanh(float x) {
    return 2.0f * __builtin_amdgcn_rcpf(1.0f + __expf(-2.0f * x)) - 1.0f;
}

// ------- fused pre-kernel: transpose(+tanh) | convw | init(+zrow) -----------
__global__ void pre_kernel(const float* __restrict__ W,
                           unsigned short* __restrict__ WT,
                           const float* __restrict__ Wih,
                           const float* __restrict__ Whh,
                           const float* __restrict__ b_ih,
                           const float* __restrict__ b_hh,
                           unsigned short* __restrict__ ih,
                           unsigned short* __restrict__ hh,
                           float* __restrict__ bsum,
                           unsigned short* __restrict__ hBuf,
                           unsigned int* __restrict__ bar,
                           unsigned short* __restrict__ zrow) {
    int bx = blockIdx.x;
    int tid = threadIdx.x;
    if (bx < TRB) {
        // WT[v][e] = fp16(tanh(Wemb[e][v])) — tanh hidden under BW
        __shared__ _Float16 tile[64][72];
        int v0 = (bx % 782) * 64;
        int e0 = (bx / 782) * 64;
        int e_loc = tid >> 2, q = tid & 3;
        int vq = q * 16;
        if (v0 + vq < VOCAB) {
            const float* src = W + (size_t)(e0 + e_loc) * VOCAB + v0 + vq;
            #pragma unroll
            for (int j = 0; j < 4; ++j) {
                f32x4 x = *(const f32x4*)(src + 4 * j);
                #pragma unroll
                for (int i = 0; i < 4; ++i)
                    tile[vq + 4 * j + i][e_loc] = (_Float16)ftanh(x[i]);
            }
        }
        __syncthreads();
        int v_loc = tid >> 2;
        int ec = q * 16;
        int v = v0 + v_loc;
        if (v < VOCAB) {
            short8* dst = (short8*)(WT + (size_t)v * EMBD + e0 + ec);
            dst[0] = *(const short8*)&tile[v_loc][ec];
            dst[1] = *(const short8*)&tile[v_loc][ec + 8];
        }
    } else if (bx < TRB + CVB) {
        int j = bx - TRB;  // 0..4095
        if (tid == 0) bsum[j] = b_ih[j] + b_hh[j];
        for (int col = tid; col < EMBD; col += blockDim.x)
            ih[(size_t)j * EMBD + col] = f16bits((_Float16)Wih[(size_t)j * EMBD + col]);
        for (int col = tid; col < HID; col += blockDim.x)
            hh[(size_t)j * HID + col] = f16bits((_Float16)Whh[(size_t)j * HID + col]);
    } else {
        int idx = (bx - TRB - CVB) * 256 + tid;   // over NB*HID
        hBuf[idx] = 0;
        if (idx < 4096) bar[idx] = 0;
        if (idx < 512) zrow[idx] = 0;
    }
}

// ------- pre-GEMM: token-indirect A-stage, LDS-staged, G0 fp16 [jl][gate] ---
__global__ __launch_bounds__(512, 2) void pregemm_kernel(
    const int* __restrict__ qv,
    const unsigned short* __restrict__ WT,    // tanh'd embeddings [50000][512]
    const unsigned short* __restrict__ zrow,  // 1KB zeros (pad token)
    const unsigned short* __restrict__ ih,
    const float* __restrict__ bsum,
    unsigned short* __restrict__ G0h)
{
    __shared__ char smem[65536];   // A dbuf [2][16KB] @0, B dbuf [2][16KB] @32768

    int id = blockIdx.x;
    int xcd = id & 7, lid = id >> 3;
    int pc = xcd * 4 + (lid & 3);   // 0..31
    int pm = lid >> 2;              // 0..51
    int m0 = pm * 128;

    int tid = threadIdx.x;
    int w = tid >> 6;               // 0..7
    int mh = w >> 2, nh = w & 3;
    int lane = tid & 63;
    int col16 = lane & 15, g4 = lane >> 4;

    int sr = lane >> 3, sc = lane & 7;
    int ra0 = w * 16 + sr, ra1 = ra0 + 8;

    // token-indirect A sources (swizzled chunk within row, per G21)
    int row0 = m0 + ra0, row1 = m0 + ra1;
    int tok0 = qv[(row0 & 255) * SEQW + (row0 >> 8)];
    int tok1 = qv[(row1 & 255) * SEQW + (row1 >> 8)];
    const char* srcA0 = (tok0 > 0)
        ? (const char*)WT + (size_t)(tok0 - 1) * 1024 + ((sc ^ (ra0 & 7)) * 16)
        : (const char*)zrow + ((sc ^ (ra0 & 7)) * 16);
    const char* srcA1 = (tok1 > 0)
        ? (const char*)WT + (size_t)(tok1 - 1) * 1024 + ((sc ^ (ra1 & 7)) * 16)
        : (const char*)zrow + ((sc ^ (ra1 & 7)) * 16);

    const char* iB = (const char*)ih;
    int gb0 = (ra0 >> 5) * 1024 + pc * 32 + (ra0 & 31);
    int gb1 = (ra1 >> 5) * 1024 + pc * 32 + (ra1 & 31);
    size_t bOffG0 = (size_t)gb0 * 1024 + (size_t)(((sc ^ (ra0 & 7))) * 16);
    size_t bOffG1 = (size_t)gb1 * 1024 + (size_t)(((sc ^ (ra1 & 7))) * 16);
    int ldsRow0 = (w * 16) * 128;
    int ldsRow1 = (w * 16 + 8) * 128;

    f32x4 acc[4][2];
    #pragma unroll
    for (int fm = 0; fm < 4; ++fm)
        #pragma unroll
        for (int fn = 0; fn < 2; ++fn)
            acc[fm][fn] = (f32x4){0.f, 0.f, 0.f, 0.f};

    int swb = col16 & 7;
    int aRow[4], bRow[2];
    #pragma unroll
    for (int fm = 0; fm < 4; ++fm) aRow[fm] = (mh * 64 + fm * 16 + col16) * 128;
    #pragma unroll
    for (int fn = 0; fn < 2; ++fn) bRow[fn] = (nh * 32 + fn * 16 + col16) * 128;

#define STAGE(kb, buf) do { \
        int kby = (kb) * 128; \
        char* aD = smem + (buf) * 16384; \
        char* bD = smem + 32768 + (buf) * 16384; \
        gload16(srcA0 + kby, aD + ldsRow0); \
        gload16(srcA1 + kby, aD + ldsRow1); \
        gload16(iB + bOffG0 + kby, bD + ldsRow0); \
        gload16(iB + bOffG1 + kby, bD + ldsRow1); \
    } while (0)

    STAGE(0, 0);
    #pragma unroll
    for (int kb = 0; kb < 8; ++kb) {
        int cur = kb & 1;
        __syncthreads();
        if (kb < 7) STAGE(kb + 1, cur ^ 1);
        const char* aS = smem + cur * 16384;
        const char* bS = smem + 32768 + cur * 16384;
        #pragma unroll
        for (int kk = 0; kk < 2; ++kk) {
            int co = ((kk * 4 + g4) ^ swb) * 16;
            half8 bF[2];
            #pragma unroll
            for (int fn = 0; fn < 2; ++fn)
                bF[fn] = *(const half8*)(const void*)(bS + bRow[fn] + co);
            #pragma unroll
            for (int fm = 0; fm < 4; ++fm) {
                half8 aF = *(const half8*)(const void*)(aS + aRow[fm] + co);
                #pragma unroll
                for (int fn = 0; fn < 2; ++fn)
                    acc[fm][fn] = __builtin_amdgcn_mfma_f32_16x16x32_f16(
                        aF, bF[fn], acc[fm][fn], 0, 0, 0);
            }
        }
    }
#undef STAGE

    // epilogue: G0h[t][ct][b][jl*4 + gate] fp16 (+bias)
    #pragma unroll
    for (int fn = 0; fn < 2; ++fn) {
        int cp = nh * 32 + fn * 16 + col16;
        int gate = cp >> 5;
        int jh = pc * 32 + (cp & 31);
        int ct = jh >> 4, jl = jh & 15;
        int cidx = jl * 4 + gate;
        float bv = bsum[gate * HID + jh];
        #pragma unroll
        for (int fm = 0; fm < 4; ++fm)
            #pragma unroll
            for (int r = 0; r < 4; ++r) {
                int row = m0 + mh * 64 + fm * 16 + g4 * 4 + r;
                int t = row >> 8, b = row & 255;
                G0h[(((size_t)t * 64 + ct) * 256 + b) * 64 + cidx] =
                    f16bits((_Float16)(acc[fm][fn][r] + bv));
            }
    }
}

// ------- persistent LSTM: R22 + (512,1) VGPR headroom + hoisted G0 prefetch -
__global__ __launch_bounds__(512, 1) void lstm_persist(
    const unsigned short* __restrict__ hh,     // fp16 Whh [4096][1024]
    unsigned short* __restrict__ hBuf,         // 27 slots of NB*HID fp16
    const unsigned short* __restrict__ G0h,    // fp16 G0 [t][ct][b][jl*4+gate]
    float* __restrict__ out,
    unsigned int* __restrict__ bar)
{
    extern __shared__ char smem[];
    // [0,65536): A [32][2048B] XOR-swizzled; [65536,133120): gbuf[4][32][132]
    float* gbuf = (float*)(smem + 65536);

    int bx = blockIdx.x;
    int grp = bx & 7;                 // XCD-local group
    int lid = bx >> 3;                // 0..31
    int m0  = grp * 32;
    int jh0 = lid * 32;

    int tid = threadIdx.x;
    int w = tid >> 6;
    int kq = w & 3, ch = w >> 2;      // K-quarter, col-half
    int lane = tid & 63;
    int col16 = lane & 15, g4 = lane >> 4;

    unsigned int* flags = bar + grp * 32;   // 32 packed flags (2 lines)

    // ---- preload B: wave's 64 gate-cols x K-quarter (256) into regs ----
    half8 bB[4][8];
    #pragma unroll
    for (int nf = 0; nf < 4; ++nf) {
        int colp = ch * 64 + nf * 16 + col16;      // 0..127
        int gate = colp >> 5, c32 = colp & 31;
        const char* bRow = (const char*)hh +
            ((size_t)(gate * HID + jh0 + c32) * HID + kq * 256 + g4 * 8) * 2;
        #pragma unroll
        for (int kk = 0; kk < 8; ++kk)
            bB[nf][kk] = *(const half8*)(const void*)(bRow + kk * 64);
    }

    int swr = (col16 & 7) << 4;
    int ml = tid >> 4, sc16 = tid & 15, jl2 = sc16 * 2;
    int jh = jh0 + jl2;
    int ctE = jh >> 4, jlE = jh & 15;

    float cReg[2] = {0.f, 0.f};

    // ---- G0 prefetch for t=0 ----
    half8 g0;
    {
        const unsigned short* pg = G0h +
            (((size_t)ctE) * 256 + (m0 + ml)) * 64 + jlE * 4;
        g0 = *(const half8*)(const void*)pg;
    }

    for (int t = 0; t < SEQW; ++t) {
        const unsigned short* hIn = hBuf + (size_t)t * NB * HID;
        unsigned short* hOut = hBuf + (size_t)(t + 1) * NB * HID;

        f32x4 acc[2][4];
        #pragma unroll
        for (int mf = 0; mf < 2; ++mf)
            #pragma unroll
            for (int nf = 0; nf < 4; ++nf)
                acc[mf][nf] = (f32x4){0.f, 0.f, 0.f, 0.f};

        if (t > 0) {
            // A stage via global_load_lds (linear dest, swizzled source)
            #pragma unroll
            for (int j = 0; j < 8; ++j) {
                int row = w * 4 + (j >> 1);
                int half_ = j & 1;
                int cs = (half_ * 64 + lane) ^ (row & 7);
                gload16((const char*)hIn + (size_t)(m0 + row) * 2048 + cs * 16,
                        smem + row * 2048 + half_ * 1024);
            }
            __syncthreads();   // drains global_load_lds before reads

            #pragma unroll
            for (int kk = 0; kk < 8; ++kk) {
                int kb = kq * 512 + kk * 64 + g4 * 16;
                int kbs = kb ^ swr;
                half8 a0 = *(const half8*)(const void*)(smem + col16 * 2048 + kbs);
                half8 a1 = *(const half8*)(const void*)(smem + (col16 + 16) * 2048 + kbs);
                #pragma unroll
                for (int nf = 0; nf < 4; ++nf) {
                    acc[0][nf] = __builtin_amdgcn_mfma_f32_16x16x32_f16(a0, bB[nf][kk], acc[0][nf], 0, 0, 0);
                    acc[1][nf] = __builtin_amdgcn_mfma_f32_16x16x32_f16(a1, bB[nf][kk], acc[1][nf], 0, 0, 0);
                }
            }
        }

        // scatter K-partials (gbuf separate region: no anti-alias sync)
        #pragma unroll
        for (int mf = 0; mf < 2; ++mf)
            #pragma unroll
            for (int nf = 0; nf < 4; ++nf) {
                int colp = ch * 64 + nf * 16 + col16;
                #pragma unroll
                for (int r = 0; r < 4; ++r)
                    gbuf[(kq * 32 + mf * 16 + g4 * 4 + r) * 132 + colp] = acc[mf][nf][r];
            }
        __syncthreads();

        float gv[4][2];
        #pragma unroll
        for (int g = 0; g < 4; ++g) {
            f32x2 s = {0.f, 0.f};
            #pragma unroll
            for (int q = 0; q < 4; ++q)
                s += *(const f32x2*)&gbuf[(q * 32 + ml) * 132 + g * 32 + jl2];
            gv[g][0] = s[0] + (float)g0[g];
            gv[g][1] = s[1] + (float)g0[4 + g];
        }

        float hN[2];
        #pragma unroll
        for (int u = 0; u < 2; ++u) {
            float si = fsig(gv[0][u]);
            float sf = fsig(gv[1][u]);
            float tg = ftanh(gv[2][u]);
            float so = fsig(gv[3][u]);
            float cN = sf * cReg[u] + si * tg;
            hN[u] = so * ftanh(cN);
            cReg[u] = cN;
        }
        size_t p = (size_t)(m0 + ml) * HID + jh;
        if (t == SEQW - 1) {
            *(f32x2*)(out + p) = (f32x2){hN[0], hN[1]};
        } else {
            // hoisted G0[t+1] prefetch (h-independent): latency hides under
            // the store/flag/poll barrier below; value carried in registers.
            half8 g0n;
            {
                const unsigned short* pg = G0h +
                    (((size_t)(t + 1) * 64 + ctE) * 256 + (m0 + ml)) * 64 + jlE * 4;
                g0n = *(const half8*)(const void*)pg;
            }

            unsigned int hv = (unsigned int)f16bits((_Float16)hN[0]) |
                              ((unsigned int)f16bits((_Float16)hN[1]) << 16);
            __hip_atomic_store((unsigned int*)(hOut + p), hv,
                               __ATOMIC_RELAXED, __HIP_MEMORY_SCOPE_AGENT);

            __syncthreads();   // ALL waves' h sc1-stores drained (L3-visible)
            unsigned int t1 = (unsigned int)(t + 1);
            if (tid == 0)
                __hip_atomic_store(flags + lid, t1,
                                   __ATOMIC_RELAXED, __HIP_MEMORY_SCOPE_AGENT);
            if (w == 0) {
                for (;;) {
                    unsigned int v = __hip_atomic_load(
                        flags + (lane & 31), __ATOMIC_RELAXED,
                        __HIP_MEMORY_SCOPE_AGENT);
                    if (__all(v >= t1)) break;
                    __builtin_amdgcn_s_sleep(1);
                }
            }
            __syncthreads();

            g0 = g0n;
        }
    }
}

extern "C" void kernel_launch(void* const* d_in, const int* in_sizes, int n_in,
                              void* d_out, int out_size, void* d_ws, size_t ws_size,
                              hipStream_t stream) {
    const int*   qv   = (const int*)d_in[0];
    const float* Wemb = (const float*)d_in[2];
    const float* Wih  = (const float*)d_in[3];
    const float* Whh  = (const float*)d_in[4];
    const float* b_ih = (const float*)d_in[5];
    const float* b_hh = (const float*)d_in[6];
    float* out = (float*)d_out;

    char* ws = (char*)d_ws;
    size_t off = 0;
    unsigned short* WT   = (unsigned short*)(ws + off); off += (size_t)VOCAB * EMBD * 2;  // 51.2 MB
    unsigned short* ih   = (unsigned short*)(ws + off); off += (size_t)NGATE * EMBD * 2;
    unsigned short* hh   = (unsigned short*)(ws + off); off += (size_t)NGATE * HID * 2;
    unsigned short* hBuf = (unsigned short*)(ws + off); off += (size_t)(SEQW + 1) * NB * HID * 2;
    float* bsum          = (float*)(ws + off);          off += (size_t)NGATE * 4;
    unsigned int* bar    = (unsigned int*)(ws + off);   off += 16384;
    unsigned short* zrow = (unsigned short*)(ws + off); off += 1024;
    off = (off + 255) & ~(size_t)255;
    unsigned short* G0h  = (unsigned short*)(ws + off); off += (size_t)MTOT * NGATE * 2;  // 54.5 MB

    pre_kernel<<<TRB + CVB + INB, 256, 0, stream>>>(
        Wemb, WT, Wih, Whh, b_ih, b_hh, ih, hh, bsum, hBuf, bar, zrow);
    pregemm_kernel<<<1664, 512, 0, stream>>>(qv, WT, zrow, ih, bsum, G0h);

    lstm_persist<<<256, 512, 133120, stream>>>(hh, hBuf, G0h, out, bar);
}